// Round 12
// baseline (95.073 us; speedup 1.0000x reference)
//
#include <hip/hip_runtime.h>
#include <stdint.h>

// N=2048, M=128, D_IN=352, H1=512, D=256, OUT_C=13.  All device tensors FLOAT32.
// Algebra: diff = A[n]-B[m] affine -> fold SharedMLP conv1 into PA2[n,32]/PB2[m,32];
// softmax over m sums to 1 -> att[n,c] = A[n,c] - sum_m wei[n,m,c]*B[m,c].
// Round 12: main_attn -> 512 threads / 8 waves (2 waves/SIMD/block): halves the
// per-wave serial chain and doubles latency-hiding TLP.  R11 evidence: 57% of
// time nothing issues, 1 wave/SIMD/block.  launch_bounds(512,2) = 256-VGPR cap
// (spill-safe).  Encoders/proj unchanged.

typedef __attribute__((ext_vector_type(4))) float float4_t;
typedef __attribute__((ext_vector_type(4))) float f32x4;
typedef __attribute__((ext_vector_type(8))) short bf16x8;
typedef __attribute__((ext_vector_type(8))) unsigned short ushort8_t;
typedef unsigned short ushort_t;

__device__ __forceinline__ unsigned short f2b(float f) {
  union { float f; unsigned int i; } v; v.f = f;
  unsigned int x = v.i;
  return (unsigned short)((x + 0x7FFFu + ((x >> 16) & 1u)) >> 16);
}

// load 8 contiguous elements as bf16, converting if source is f32
template<int ISBF>
__device__ __forceinline__ ushort8_t ld8(const void* base, size_t idx) {
  if constexpr (ISBF) {
    return *(const ushort8_t*)((const ushort_t*)base + idx);
  } else {
    const float* p = (const float*)base + idx;
    float4_t v0 = *(const float4_t*)p;
    float4_t v1 = *(const float4_t*)(p + 4);
    ushort8_t u;
    #pragma unroll
    for (int e = 0; e < 4; ++e) { u[e] = f2b(v0[e]); u[4 + e] = f2b(v1[e]); }
    return u;
  }
}

// ---------- MFMA encoder: Y = relu(g*(X @ W^T + b) + be); 32x32 tile ----------
template<int XBF, int WBF, int OUT_BF16>
__global__ __launch_bounds__(256) void enc_mfma(
    const void* __restrict__ XA, const void* __restrict__ WA,
    const float* __restrict__ bA, const float* __restrict__ gA, const float* __restrict__ beA,
    void* __restrict__ YA,
    const void* __restrict__ XB, const void* __restrict__ WB,
    const float* __restrict__ bB, const float* __restrict__ gB, const float* __restrict__ beB,
    void* __restrict__ YB, float* __restrict__ YBT,
    int J, int K, int nbxA)
{
  __shared__ ushort_t Xs[2][32][40];
  __shared__ ushort_t Ws[2][32][40];
  const int bx = blockIdx.x, by = blockIdx.y;
  const void* X; const void* W;
  const float *bb, *gg, *bev; void* Y; int i0, isB;
  if (bx < nbxA) { X = XA; W = WA; bb = bA; gg = gA; bev = beA; Y = YA; i0 = bx * 32; isB = 0; }
  else           { X = XB; W = WB; bb = bB; gg = gB; bev = beB; Y = YB; i0 = (bx - nbxA) * 32; isB = 1; }
  const int j0 = by * 32;
  const int tid = threadIdx.x, w = tid >> 6, lane = tid & 63, lg = lane >> 4, lr = lane & 15;
  const int mt = w >> 1, ct = w & 1;
  const int row = tid >> 2, k8 = (tid & 3) * 8;   // rows 0..31 stage X, 32..63 stage W

  f32x4 acc = f32x4{0.f, 0.f, 0.f, 0.f};

  ushort8_t sv = (row < 32) ? ld8<XBF>(X, (size_t)(i0 + row) * K + k8)
                            : ld8<WBF>(W, (size_t)(j0 + row - 32) * K + k8);
  for (int kt = 0; kt < K; kt += 32) {
    const int buf = (kt >> 5) & 1;
    if (row < 32) *(ushort8_t*)&Xs[buf][row][k8] = sv;
    else          *(ushort8_t*)&Ws[buf][row - 32][k8] = sv;
    __syncthreads();
    if (kt + 32 < K)
      sv = (row < 32) ? ld8<XBF>(X, (size_t)(i0 + row) * K + kt + 32 + k8)
                      : ld8<WBF>(W, (size_t)(j0 + row - 32) * K + kt + 32 + k8);
    bf16x8 af = *(const bf16x8*)&Xs[buf][mt * 16 + lr][lg * 8];
    bf16x8 bf_ = *(const bf16x8*)&Ws[buf][ct * 16 + lr][lg * 8];
    acc = __builtin_amdgcn_mfma_f32_16x16x32_bf16(af, bf_, acc, 0, 0, 0);
  }
  const int c = j0 + ct * 16 + lr;
  const float g = gg[c], bv = bb[c], ev = bev[c];
  #pragma unroll
  for (int r = 0; r < 4; ++r) {
    const int rowo = i0 + mt * 16 + 4 * lg + r;
    float t = fmaxf(g * (acc[r] + bv) + ev, 0.f);
    if (OUT_BF16) ((ushort_t*)Y)[(size_t)rowo * J + c] = f2b(t);
    else {
      ((float*)Y)[(size_t)rowo * J + c] = t;
      if (isB && YBT) YBT[(size_t)c * 128 + rowo] = t;
    }
  }
}

// ---------- proj: P = fold(X @ mw1^T); 4 rows/block, split-K-2; + cvt tail ----------
__global__ __launch_bounds__(256) void proj32(
    const float* __restrict__ Aenc, const float* __restrict__ Benc,
    const float* __restrict__ mw1, const float* __restrict__ mb1,
    const float* __restrict__ mg1, const float* __restrict__ mbe1,
    float* __restrict__ PA2, float* __restrict__ PB2, int nbxA,
    const float* __restrict__ mw2, const float* __restrict__ mw3,
    ushort_t* __restrict__ mw2b, ushort_t* __restrict__ mw3b)
{
  __shared__ float ps[4][32];
  const int tid = threadIdx.x, bx = blockIdx.x;
  if (bx >= nbxA + 32) {
    const int g = (bx - nbxA - 32) * 256 + tid;   // 2304 groups of 8
    const float* s; ushort_t* d; int j;
    if (g < 256) { s = mw2; d = mw2b; j = g; }
    else         { s = mw3; d = mw3b; j = g - 256; }
    float4_t v0 = *(const float4_t*)&s[(size_t)j * 8];
    float4_t v1 = *(const float4_t*)&s[(size_t)j * 8 + 4];
    ushort8_t u;
    #pragma unroll
    for (int e = 0; e < 4; ++e) { u[e] = f2b(v0[e]); u[4 + e] = f2b(v1[e]); }
    *(ushort8_t*)&d[(size_t)j * 8] = u;
    return;
  }
  const float* X; float* P; int n0, wb;
  if (bx < nbxA) { X = Aenc; P = PA2; n0 = bx * 4; wb = 1; }
  else           { X = Benc; P = PB2; n0 = (bx - nbxA) * 4; wb = 0; }
  const int k = tid & 31, r = (tid >> 5) & 3, half = tid >> 7;
  const int n = n0 + r;
  const float* xp = &X[(size_t)n * 256 + half * 128];
  const float* wp = &mw1[k * 256 + half * 128];
  float s = 0.f;
  #pragma unroll 8
  for (int q = 0; q < 128; q += 4) {
    float4_t xv = *(const float4_t*)&xp[q];
    float4_t wv = *(const float4_t*)&wp[q];
    #pragma unroll
    for (int e = 0; e < 4; ++e) s = fmaf(xv[e], wv[e], s);
  }
  if (half == 1) ps[r][k] = s;
  __syncthreads();
  if (half == 0) {
    s += ps[r][k];
    P[(size_t)n * 32 + k] = wb ? (mg1[k] * (s + mb1[k]) + mbe1[k]) : (mg1[k] * s);
  }
}

// ---------- fused main kernel: 2 n per block, 512 threads (8 waves), grid 1024 ----------
// MFMA 16x16x32_bf16: A frag m=lane&15,k=(lane>>4)*8+e; B frag c=lane&15,same k;
// C/D col=lane&15,row=(lane>>4)*4+reg.
// Wave w: phase1 owns m in [w*16,(w+1)*16); phase2/softmax owns c in [w*32,(w+1)*32).
// Softmax: relu'd logits >= 0, shift-invariant -> p = exp2(med3(l,0,80)), no max.
// LDS 42240B: h2s dbuf 2x18432 | attLs[2][256] f32 @36864 | part[2][13][32] @38912.
__global__ __launch_bounds__(512, 2) void main_attn(
    const float* __restrict__ PA2, const float* __restrict__ PB2,
    const float* __restrict__ A, const float* __restrict__ BmT,
    const ushort_t* __restrict__ mw2b, const float* __restrict__ mb2,
    const float* __restrict__ mg2, const float* __restrict__ mbe2,
    const ushort_t* __restrict__ mw3b, const float* __restrict__ mb3,
    const float* __restrict__ mg3, const float* __restrict__ mbe3,
    const float* __restrict__ fcw, const float* __restrict__ fcb,
    float* __restrict__ outp)
{
  __shared__ __align__(16) char smem[42240];
  float* attLs = (float*)(smem + 36864);   // [2][256]
  float* part  = (float*)(smem + 38912);   // [2][13*32]

  const int tid = threadIdx.x;
  const int w = tid >> 6, lane = tid & 63, lg = lane >> 4, lr = lane & 15;
  const int n0 = blockIdx.x * 2;
  const float LOG2E = 1.4426950408889634f;

  // hoists (n-independent)
  float g2h[4], b2h[4], e2h[4];
  #pragma unroll
  for (int jt = 0; jt < 4; ++jt) {
    const int j = jt * 16 + lr;
    g2h[jt] = mg2[j]; b2h[jt] = mb2[j]; e2h[jt] = mbe2[j];
  }
  float gs3[2], cs3[2];
  #pragma unroll
  for (int ct = 0; ct < 2; ++ct) {
    const int c = w * 32 + ct * 16 + lr;
    const float g = mg3[c];
    gs3[ct] = g * LOG2E;
    cs3[ct] = (g * mb3[c] + mbe3[c]) * LOG2E;
  }

  #pragma unroll
  for (int nn = 0; nn < 2; ++nn) {
    const int n = n0 + nn;
    ushort_t* h2s = (ushort_t*)(smem + nn * 18432);

    // ---- phase1: h2[m][j] for m in [w*16,(w+1)*16) -> h2s ----
    {
      f32x4 acc1[4];
      #pragma unroll
      for (int jt = 0; jt < 4; ++jt) acc1[jt] = f32x4{0.f, 0.f, 0.f, 0.f};
      bf16x8 a1, b1[4];
      {
        const float* pa = &PA2[(size_t)n * 32 + lg * 8];
        float4_t pa0 = *(const float4_t*)pa;
        float4_t pa1 = *(const float4_t*)(pa + 4);
        const int m = w * 16 + lr;
        const float* pb = &PB2[(size_t)m * 32 + lg * 8];
        float4_t pb0 = *(const float4_t*)pb;
        float4_t pb1 = *(const float4_t*)(pb + 4);
        bf16x8 u;
        #pragma unroll
        for (int e = 0; e < 4; ++e) {
          u[e]     = (short)f2b(fmaxf(pa0[e] - pb0[e], 0.f));
          u[4 + e] = (short)f2b(fmaxf(pa1[e] - pb1[e], 0.f));
        }
        a1 = u;
      }
      #pragma unroll
      for (int jt = 0; jt < 4; ++jt)
        b1[jt] = *(const bf16x8*)&mw2b[(jt * 16 + lr) * 32 + lg * 8];
      #pragma unroll
      for (int jt = 0; jt < 4; ++jt)
        acc1[jt] = __builtin_amdgcn_mfma_f32_16x16x32_bf16(a1, b1[jt], acc1[jt], 0, 0, 0);
      #pragma unroll
      for (int jt = 0; jt < 4; ++jt)
        #pragma unroll
        for (int r = 0; r < 4; ++r)
          h2s[(w * 16 + 4 * lg + r) * 72 + jt * 16 + lr] =
              f2b(fmaxf(g2h[jt] * (acc1[jt][r] + b2h[jt]) + e2h[jt], 0.f));
    }
    __syncthreads();   // h2s[nn] visible; also orders buffer reuse across nn

    // ---- phase2: wave w owns c in [w*32,(w+1)*32): 2 ct x 8 mt x 2 ks ----
    f32x4 acc[8][2];
    #pragma unroll
    for (int mt = 0; mt < 8; ++mt) {
      acc[mt][0] = f32x4{0.f, 0.f, 0.f, 0.f};
      acc[mt][1] = f32x4{0.f, 0.f, 0.f, 0.f};
    }
    #pragma unroll
    for (int ks = 0; ks < 2; ++ks) {
      bf16x8 bfr[2];
      #pragma unroll
      for (int q = 0; q < 2; ++q) {
        const int c = w * 32 + q * 16 + lr;
        bfr[q] = *(const bf16x8*)&mw3b[(size_t)c * 64 + ks * 32 + lg * 8];
      }
      #pragma unroll
      for (int mt = 0; mt < 8; ++mt) {
        bf16x8 af = *(const bf16x8*)&h2s[(mt * 16 + lr) * 72 + ks * 32 + lg * 8];
        acc[mt][0] = __builtin_amdgcn_mfma_f32_16x16x32_bf16(af, bfr[0], acc[mt][0], 0, 0, 0);
        acc[mt][1] = __builtin_amdgcn_mfma_f32_16x16x32_bf16(af, bfr[1], acc[mt][1], 0, 0, 0);
      }
    }

    // ---- single-pass no-max softmax over m for 2 ct tiles ----
    float smv[2], wbv[2];
    #pragma unroll
    for (int q = 0; q < 2; ++q) {
      const int c = w * 32 + q * 16 + lr;
      f32x4 sm4 = f32x4{0.f, 0.f, 0.f, 0.f};
      f32x4 wb4 = f32x4{0.f, 0.f, 0.f, 0.f};
      #pragma unroll
      for (int mt = 0; mt < 8; ++mt) {
        float4_t bv4 = *(const float4_t*)&BmT[(size_t)c * 128 + mt * 16 + 4 * lg];
        #pragma unroll
        for (int r = 0; r < 4; ++r) {
          float t = fmaf(gs3[q], acc[mt][q][r], cs3[q]);
          float p = __builtin_amdgcn_exp2f(__builtin_amdgcn_fmed3f(t, 0.f, 80.f));
          sm4[r] += p;
          wb4[r] = fmaf(p, bv4[r], wb4[r]);
        }
      }
      smv[q] = (sm4[0] + sm4[1]) + (sm4[2] + sm4[3]);
      wbv[q] = (wb4[0] + wb4[1]) + (wb4[2] + wb4[3]);
    }
    // merge the 4 lane-groups (m-partition): plain adds
    #pragma unroll
    for (int st = 16; st <= 32; st <<= 1) {
      #pragma unroll
      for (int q = 0; q < 2; ++q) {
        smv[q] += __shfl_xor(smv[q], st, 64);
        wbv[q] += __shfl_xor(wbv[q], st, 64);
      }
    }
    if (lg == 0) {
      #pragma unroll
      for (int q = 0; q < 2; ++q) {
        const int c = w * 32 + q * 16 + lr;
        attLs[nn * 256 + c] = A[(size_t)n * 256 + c] - wbv[q] / smv[q];
      }
    }
    // no barrier here: softmax tail of n overlaps phase1 of n+1
  }
  __syncthreads();

  // ---- fc for both n: out[o] = fcb[o] + sum_c attL[c]*fcw[o][c] ----
  {
    const int o = tid >> 5, gp = tid & 31;   // 32 partials per o, 8 c each
    if (o < 13) {
      float4_t wv[2];
      #pragma unroll
      for (int i = 0; i < 2; ++i)
        wv[i] = *(const float4_t*)&fcw[(size_t)o * 256 + gp * 8 + i * 4];
      #pragma unroll
      for (int nn = 0; nn < 2; ++nn) {
        float s = 0.f;
        #pragma unroll
        for (int i = 0; i < 2; ++i) {
          float4_t av = *(const float4_t*)&attLs[nn * 256 + gp * 8 + i * 4];
          #pragma unroll
          for (int e = 0; e < 4; ++e) s = fmaf(av[e], wv[i][e], s);
        }
        part[nn * 416 + o * 32 + gp] = s;
      }
    }
  }
  __syncthreads();
  if (tid < 26) {
    const int nn = tid / 13, o = tid % 13;
    float s = fcb[o];
    #pragma unroll
    for (int gp = 0; gp < 32; ++gp) s += part[nn * 416 + o * 32 + gp];
    outp[(size_t)(n0 + nn) * 13 + o] = s;
  }
}

extern "C" void kernel_launch(void* const* d_in, const int* in_sizes, int n_in,
                              void* d_out, int out_size, void* d_ws, size_t ws_size,
                              hipStream_t stream)
{
  const float* ext = (const float*)d_in[0];
  const float* lab = (const float*)d_in[1];
  const float* w1a = (const float*)d_in[2];
  const float* b1a = (const float*)d_in[3];
  const float* g1a = (const float*)d_in[4];
  const float* be1a= (const float*)d_in[5];
  const float* w1b = (const float*)d_in[6];
  const float* b1b = (const float*)d_in[7];
  const float* g1b = (const float*)d_in[8];
  const float* be1b= (const float*)d_in[9];
  const float* w2a = (const float*)d_in[10];
  const float* b2a = (const float*)d_in[11];
  const float* g2a = (const float*)d_in[12];
  const float* be2a= (const float*)d_in[13];
  const float* w2b = (const float*)d_in[14];
  const float* b2b = (const float*)d_in[15];
  const float* g2b = (const float*)d_in[16];
  const float* be2b= (const float*)d_in[17];
  const float* mw1 = (const float*)d_in[18];
  const float* mb1 = (const float*)d_in[19];
  const float* mg1 = (const float*)d_in[20];
  const float* mbe1= (const float*)d_in[21];
  const float* mw2 = (const float*)d_in[22];
  const float* mb2 = (const float*)d_in[23];
  const float* mg2 = (const float*)d_in[24];
  const float* mbe2= (const float*)d_in[25];
  const float* mw3 = (const float*)d_in[26];
  const float* mb3 = (const float*)d_in[27];
  const float* mg3 = (const float*)d_in[28];
  const float* mbe3= (const float*)d_in[29];
  const float* fcw = (const float*)d_in[30];
  const float* fcb = (const float*)d_in[31];

  char* ws = (char*)d_ws;
  ushort_t* Y1ab = (ushort_t*)(ws);                       // [0,2M) bf16 2048x512 (dead after enc2)
  float*    PA2  = (float*)(ws);                          // [0,256K) written by proj
  float*    PB2  = (float*)(ws + 262144);                 // [256K,272K)
  float*    Aenc = (float*)(ws + (2u << 20));             // [2M,4M) f32 2048x256
  char* b5 = ws + (4u << 20);
  ushort_t* mw2b = (ushort_t*)(b5);                       // 64x32 bf16 (4KB)
  ushort_t* mw3b = (ushort_t*)(b5 + 4096);                // 256x64 bf16 (32KB)
  ushort_t* Y1bb = (ushort_t*)(b5 + 36864);               // 128x512 bf16 (128KB)
  float*    Benc = (float*)(b5 + 167936);                 // 128x256 f32 (128KB)
  float*    BencT= (float*)(b5 + 299008);                 // 256x128 f32 (128KB)

  enc_mfma<0, 0, 1><<<dim3(68, 16), 256, 0, stream>>>(
      (const void*)ext, (const void*)w1a, b1a, g1a, be1a, (void*)Y1ab,
      (const void*)lab, (const void*)w2a, b2a, g2a, be2a, (void*)Y1bb,
      (float*)nullptr, 512, 352, 64);
  enc_mfma<1, 0, 0><<<dim3(68, 8), 256, 0, stream>>>(
      (const void*)Y1ab, (const void*)w1b, b1b, g1b, be1b, (void*)Aenc,
      (const void*)Y1bb, (const void*)w2b, b2b, g2b, be2b, (void*)Benc,
      BencT, 256, 512, 64);
  proj32<<<553, 256, 0, stream>>>(Aenc, Benc, mw1, mb1, mg1, mbe1, PA2, PB2, 512,
                                  mw2, mw3, mw2b, mw3b);
  main_attn<<<1024, 512, 0, stream>>>(PA2, PB2, Aenc, BencT,
                                      mw2b, mb2, mg2, mbe2, mw3b, mb3, mg3, mbe3,
                                      fcw, fcb, (float*)d_out);
}

// Round 13
// 86.337 us; speedup vs baseline: 1.1012x; 1.1012x over previous
//
#include <hip/hip_runtime.h>
#include <stdint.h>

// N=2048, M=128, D_IN=352, H1=512, D=256, OUT_C=13.  All device tensors FLOAT32.
// Algebra: diff = A[n]-B[m] affine -> fold SharedMLP conv1 into PA2[n,32]/PB2[m,32];
// softmax over m sums to 1 -> att[n,c] = A[n,c] - sum_m wei[n,m,c]*B[m,c].
// Round 13: ZERO-BARRIER main_attn.  One wave = one n, private LDS slab
// (h2[128][72] + att[256]); all LDS deps intra-wave (no __syncthreads at all).
// 4 waves/block, 77.8KB LDS, 2 blocks/CU -> 8 decorrelated wave-pipelines/CU.
// R12 falsified TLP theory (8 waves/block -> worse); constant across R7-R12 was
// barrier-coupled phases -> correlated stalls.  Encoders/proj unchanged.

typedef __attribute__((ext_vector_type(4))) float float4_t;
typedef __attribute__((ext_vector_type(4))) float f32x4;
typedef __attribute__((ext_vector_type(8))) short bf16x8;
typedef __attribute__((ext_vector_type(8))) unsigned short ushort8_t;
typedef unsigned short ushort_t;

__device__ __forceinline__ unsigned short f2b(float f) {
  union { float f; unsigned int i; } v; v.f = f;
  unsigned int x = v.i;
  return (unsigned short)((x + 0x7FFFu + ((x >> 16) & 1u)) >> 16);
}

// load 8 contiguous elements as bf16, converting if source is f32
template<int ISBF>
__device__ __forceinline__ ushort8_t ld8(const void* base, size_t idx) {
  if constexpr (ISBF) {
    return *(const ushort8_t*)((const ushort_t*)base + idx);
  } else {
    const float* p = (const float*)base + idx;
    float4_t v0 = *(const float4_t*)p;
    float4_t v1 = *(const float4_t*)(p + 4);
    ushort8_t u;
    #pragma unroll
    for (int e = 0; e < 4; ++e) { u[e] = f2b(v0[e]); u[4 + e] = f2b(v1[e]); }
    return u;
  }
}

// ---------- MFMA encoder: Y = relu(g*(X @ W^T + b) + be); 32x32 tile ----------
template<int XBF, int WBF, int OUT_BF16>
__global__ __launch_bounds__(256) void enc_mfma(
    const void* __restrict__ XA, const void* __restrict__ WA,
    const float* __restrict__ bA, const float* __restrict__ gA, const float* __restrict__ beA,
    void* __restrict__ YA,
    const void* __restrict__ XB, const void* __restrict__ WB,
    const float* __restrict__ bB, const float* __restrict__ gB, const float* __restrict__ beB,
    void* __restrict__ YB, float* __restrict__ YBT,
    int J, int K, int nbxA)
{
  __shared__ ushort_t Xs[2][32][40];
  __shared__ ushort_t Ws[2][32][40];
  const int bx = blockIdx.x, by = blockIdx.y;
  const void* X; const void* W;
  const float *bb, *gg, *bev; void* Y; int i0, isB;
  if (bx < nbxA) { X = XA; W = WA; bb = bA; gg = gA; bev = beA; Y = YA; i0 = bx * 32; isB = 0; }
  else           { X = XB; W = WB; bb = bB; gg = gB; bev = beB; Y = YB; i0 = (bx - nbxA) * 32; isB = 1; }
  const int j0 = by * 32;
  const int tid = threadIdx.x, w = tid >> 6, lane = tid & 63, lg = lane >> 4, lr = lane & 15;
  const int mt = w >> 1, ct = w & 1;
  const int row = tid >> 2, k8 = (tid & 3) * 8;   // rows 0..31 stage X, 32..63 stage W

  f32x4 acc = f32x4{0.f, 0.f, 0.f, 0.f};

  ushort8_t sv = (row < 32) ? ld8<XBF>(X, (size_t)(i0 + row) * K + k8)
                            : ld8<WBF>(W, (size_t)(j0 + row - 32) * K + k8);
  for (int kt = 0; kt < K; kt += 32) {
    const int buf = (kt >> 5) & 1;
    if (row < 32) *(ushort8_t*)&Xs[buf][row][k8] = sv;
    else          *(ushort8_t*)&Ws[buf][row - 32][k8] = sv;
    __syncthreads();
    if (kt + 32 < K)
      sv = (row < 32) ? ld8<XBF>(X, (size_t)(i0 + row) * K + kt + 32 + k8)
                      : ld8<WBF>(W, (size_t)(j0 + row - 32) * K + kt + 32 + k8);
    bf16x8 af = *(const bf16x8*)&Xs[buf][mt * 16 + lr][lg * 8];
    bf16x8 bf_ = *(const bf16x8*)&Ws[buf][ct * 16 + lr][lg * 8];
    acc = __builtin_amdgcn_mfma_f32_16x16x32_bf16(af, bf_, acc, 0, 0, 0);
  }
  const int c = j0 + ct * 16 + lr;
  const float g = gg[c], bv = bb[c], ev = bev[c];
  #pragma unroll
  for (int r = 0; r < 4; ++r) {
    const int rowo = i0 + mt * 16 + 4 * lg + r;
    float t = fmaxf(g * (acc[r] + bv) + ev, 0.f);
    if (OUT_BF16) ((ushort_t*)Y)[(size_t)rowo * J + c] = f2b(t);
    else {
      ((float*)Y)[(size_t)rowo * J + c] = t;
      if (isB && YBT) YBT[(size_t)c * 128 + rowo] = t;
    }
  }
}

// ---------- proj: P = fold(X @ mw1^T); 4 rows/block, split-K-2; + cvt tail ----------
__global__ __launch_bounds__(256) void proj32(
    const float* __restrict__ Aenc, const float* __restrict__ Benc,
    const float* __restrict__ mw1, const float* __restrict__ mb1,
    const float* __restrict__ mg1, const float* __restrict__ mbe1,
    float* __restrict__ PA2, float* __restrict__ PB2, int nbxA,
    const float* __restrict__ mw2, const float* __restrict__ mw3,
    ushort_t* __restrict__ mw2b, ushort_t* __restrict__ mw3b)
{
  __shared__ float ps[4][32];
  const int tid = threadIdx.x, bx = blockIdx.x;
  if (bx >= nbxA + 32) {
    const int g = (bx - nbxA - 32) * 256 + tid;   // 2304 groups of 8
    const float* s; ushort_t* d; int j;
    if (g < 256) { s = mw2; d = mw2b; j = g; }
    else         { s = mw3; d = mw3b; j = g - 256; }
    float4_t v0 = *(const float4_t*)&s[(size_t)j * 8];
    float4_t v1 = *(const float4_t*)&s[(size_t)j * 8 + 4];
    ushort8_t u;
    #pragma unroll
    for (int e = 0; e < 4; ++e) { u[e] = f2b(v0[e]); u[4 + e] = f2b(v1[e]); }
    *(ushort8_t*)&d[(size_t)j * 8] = u;
    return;
  }
  const float* X; float* P; int n0, wb;
  if (bx < nbxA) { X = Aenc; P = PA2; n0 = bx * 4; wb = 1; }
  else           { X = Benc; P = PB2; n0 = (bx - nbxA) * 4; wb = 0; }
  const int k = tid & 31, r = (tid >> 5) & 3, half = tid >> 7;
  const int n = n0 + r;
  const float* xp = &X[(size_t)n * 256 + half * 128];
  const float* wp = &mw1[k * 256 + half * 128];
  float s = 0.f;
  #pragma unroll 8
  for (int q = 0; q < 128; q += 4) {
    float4_t xv = *(const float4_t*)&xp[q];
    float4_t wv = *(const float4_t*)&wp[q];
    #pragma unroll
    for (int e = 0; e < 4; ++e) s = fmaf(xv[e], wv[e], s);
  }
  if (half == 1) ps[r][k] = s;
  __syncthreads();
  if (half == 0) {
    s += ps[r][k];
    P[(size_t)n * 32 + k] = wb ? (mg1[k] * (s + mb1[k]) + mbe1[k]) : (mg1[k] * s);
  }
}

// ---------- fused main kernel: ONE WAVE = ONE N, zero barriers ----------
// MFMA 16x16x32_bf16: A frag m=lane&15,k=(lane>>4)*8+e; B frag c=lane&15,same k;
// C/D col=lane&15,row=(lane>>4)*4+reg.
// Per-wave private slab: h2[128][72] bf16 (18432B) + att[256] f32 (1024B) = 19456B.
// 4 waves/block -> 77824B LDS, 2 blocks/CU, 8 independent pipelines/CU.
// All LDS dependencies are intra-wave: NO __syncthreads in this kernel.
// Softmax: relu'd logits >= 0, shift-invariant -> p = exp2(med3(l,0,80)), no max.
__global__ __launch_bounds__(256, 2) void main_attn(
    const float* __restrict__ PA2, const float* __restrict__ PB2,
    const float* __restrict__ A, const float* __restrict__ BmT,
    const ushort_t* __restrict__ mw2b, const float* __restrict__ mb2,
    const float* __restrict__ mg2, const float* __restrict__ mbe2,
    const ushort_t* __restrict__ mw3b, const float* __restrict__ mb3,
    const float* __restrict__ mg3, const float* __restrict__ mbe3,
    const float* __restrict__ fcw, const float* __restrict__ fcb,
    float* __restrict__ outp)
{
  __shared__ __align__(16) char smem[77824];
  const int tid = threadIdx.x;
  const int w = tid >> 6, lane = tid & 63, lg = lane >> 4, lr = lane & 15;
  const int n = blockIdx.x * 4 + w;
  ushort_t* h2s = (ushort_t*)(smem + w * 19456);
  float* attL   = (float*)(smem + w * 19456 + 18432);
  const float LOG2E = 1.4426950408889634f;

  // ---- phase1: h2[m][j] = relu(g2*(relu(PA2[n]-PB2[m]) @ mw2^T + b2) + be2) ----
  // processed in 8 mt-chunks; acc live = 16 f32 per chunk; no cross-wave deps
  {
    bf16x8 b1[4];
    float g2h[4], b2h[4], e2h[4];
    #pragma unroll
    for (int jt = 0; jt < 4; ++jt) {
      b1[jt] = *(const bf16x8*)&mw2b[(jt * 16 + lr) * 32 + lg * 8];
      const int j = jt * 16 + lr;
      g2h[jt] = mg2[j]; b2h[jt] = mb2[j]; e2h[jt] = mbe2[j];
    }
    const float* pa = &PA2[(size_t)n * 32 + lg * 8];
    float4_t pa0 = *(const float4_t*)pa;
    float4_t pa1 = *(const float4_t*)(pa + 4);
    #pragma unroll
    for (int mt = 0; mt < 8; ++mt) {
      const int m = mt * 16 + lr;
      const float* pb = &PB2[(size_t)m * 32 + lg * 8];
      float4_t pb0 = *(const float4_t*)pb;
      float4_t pb1 = *(const float4_t*)(pb + 4);
      bf16x8 a1;
      #pragma unroll
      for (int e = 0; e < 4; ++e) {
        a1[e]     = (short)f2b(fmaxf(pa0[e] - pb0[e], 0.f));
        a1[4 + e] = (short)f2b(fmaxf(pa1[e] - pb1[e], 0.f));
      }
      f32x4 acc1[4];
      #pragma unroll
      for (int jt = 0; jt < 4; ++jt) acc1[jt] = f32x4{0.f, 0.f, 0.f, 0.f};
      #pragma unroll
      for (int jt = 0; jt < 4; ++jt)
        acc1[jt] = __builtin_amdgcn_mfma_f32_16x16x32_bf16(a1, b1[jt], acc1[jt], 0, 0, 0);
      #pragma unroll
      for (int jt = 0; jt < 4; ++jt)
        #pragma unroll
        for (int r = 0; r < 4; ++r)
          h2s[(mt * 16 + 4 * lg + r) * 72 + jt * 16 + lr] =
              f2b(fmaxf(g2h[jt] * (acc1[jt][r] + b2h[jt]) + e2h[jt], 0.f));
    }
  }
  // (compiler inserts lgkmcnt before first dependent ds_read; same-wave ordering)

  // ---- phase2 + softmax: 16 ct-iterations, each fully in-wave ----
  #pragma unroll 2
  for (int ct = 0; ct < 16; ++ct) {
    const int c = ct * 16 + lr;
    bf16x8 bfr0 = *(const bf16x8*)&mw3b[(size_t)c * 64 + lg * 8];
    bf16x8 bfr1 = *(const bf16x8*)&mw3b[(size_t)c * 64 + 32 + lg * 8];
    f32x4 acc[8];
    #pragma unroll
    for (int mt = 0; mt < 8; ++mt) acc[mt] = f32x4{0.f, 0.f, 0.f, 0.f};
    #pragma unroll
    for (int mt = 0; mt < 8; ++mt) {
      bf16x8 af0 = *(const bf16x8*)&h2s[(mt * 16 + lr) * 72 + lg * 8];
      acc[mt] = __builtin_amdgcn_mfma_f32_16x16x32_bf16(af0, bfr0, acc[mt], 0, 0, 0);
      bf16x8 af1 = *(const bf16x8*)&h2s[(mt * 16 + lr) * 72 + 32 + lg * 8];
      acc[mt] = __builtin_amdgcn_mfma_f32_16x16x32_bf16(af1, bfr1, acc[mt], 0, 0, 0);
    }
    const float g = mg3[c];
    const float gs = g * LOG2E;
    const float cs = (g * mb3[c] + mbe3[c]) * LOG2E;
    f32x4 sm4 = f32x4{0.f, 0.f, 0.f, 0.f};
    f32x4 wb4 = f32x4{0.f, 0.f, 0.f, 0.f};
    #pragma unroll
    for (int mt = 0; mt < 8; ++mt) {
      float4_t bv4 = *(const float4_t*)&BmT[(size_t)c * 128 + mt * 16 + 4 * lg];
      #pragma unroll
      for (int r = 0; r < 4; ++r) {
        float t = fmaf(gs, acc[mt][r], cs);
        float p = __builtin_amdgcn_exp2f(__builtin_amdgcn_fmed3f(t, 0.f, 80.f));
        sm4[r] += p;
        wb4[r] = fmaf(p, bv4[r], wb4[r]);
      }
    }
    float sm = (sm4[0] + sm4[1]) + (sm4[2] + sm4[3]);
    float wb = (wb4[0] + wb4[1]) + (wb4[2] + wb4[3]);
    sm += __shfl_xor(sm, 16, 64);  wb += __shfl_xor(wb, 16, 64);
    sm += __shfl_xor(sm, 32, 64);  wb += __shfl_xor(wb, 32, 64);
    if (lg == 0)
      attL[c] = A[(size_t)n * 256 + c] - wb / sm;
  }

  // ---- fc (intra-wave): lane covers c = lane*4..lane*4+3 ----
  {
    float4_t av = *(const float4_t*)&attL[lane * 4];
    #pragma unroll
    for (int o = 0; o < 13; ++o) {
      float4_t wv = *(const float4_t*)&fcw[(size_t)o * 256 + lane * 4];
      float s = av[0] * wv[0];
      s = fmaf(av[1], wv[1], s);
      s = fmaf(av[2], wv[2], s);
      s = fmaf(av[3], wv[3], s);
      #pragma unroll
      for (int st = 1; st <= 32; st <<= 1) s += __shfl_xor(s, st, 64);
      if (lane == 0) outp[(size_t)n * 13 + o] = s + fcb[o];
    }
  }
}

extern "C" void kernel_launch(void* const* d_in, const int* in_sizes, int n_in,
                              void* d_out, int out_size, void* d_ws, size_t ws_size,
                              hipStream_t stream)
{
  const float* ext = (const float*)d_in[0];
  const float* lab = (const float*)d_in[1];
  const float* w1a = (const float*)d_in[2];
  const float* b1a = (const float*)d_in[3];
  const float* g1a = (const float*)d_in[4];
  const float* be1a= (const float*)d_in[5];
  const float* w1b = (const float*)d_in[6];
  const float* b1b = (const float*)d_in[7];
  const float* g1b = (const float*)d_in[8];
  const float* be1b= (const float*)d_in[9];
  const float* w2a = (const float*)d_in[10];
  const float* b2a = (const float*)d_in[11];
  const float* g2a = (const float*)d_in[12];
  const float* be2a= (const float*)d_in[13];
  const float* w2b = (const float*)d_in[14];
  const float* b2b = (const float*)d_in[15];
  const float* g2b = (const float*)d_in[16];
  const float* be2b= (const float*)d_in[17];
  const float* mw1 = (const float*)d_in[18];
  const float* mb1 = (const float*)d_in[19];
  const float* mg1 = (const float*)d_in[20];
  const float* mbe1= (const float*)d_in[21];
  const float* mw2 = (const float*)d_in[22];
  const float* mb2 = (const float*)d_in[23];
  const float* mg2 = (const float*)d_in[24];
  const float* mbe2= (const float*)d_in[25];
  const float* mw3 = (const float*)d_in[26];
  const float* mb3 = (const float*)d_in[27];
  const float* mg3 = (const float*)d_in[28];
  const float* mbe3= (const float*)d_in[29];
  const float* fcw = (const float*)d_in[30];
  const float* fcb = (const float*)d_in[31];

  char* ws = (char*)d_ws;
  ushort_t* Y1ab = (ushort_t*)(ws);                       // [0,2M) bf16 2048x512 (dead after enc2)
  float*    PA2  = (float*)(ws);                          // [0,256K) written by proj
  float*    PB2  = (float*)(ws + 262144);                 // [256K,272K)
  float*    Aenc = (float*)(ws + (2u << 20));             // [2M,4M) f32 2048x256
  char* b5 = ws + (4u << 20);
  ushort_t* mw2b = (ushort_t*)(b5);                       // 64x32 bf16 (4KB)
  ushort_t* mw3b = (ushort_t*)(b5 + 4096);                // 256x64 bf16 (32KB)
  ushort_t* Y1bb = (ushort_t*)(b5 + 36864);               // 128x512 bf16 (128KB)
  float*    Benc = (float*)(b5 + 167936);                 // 128x256 f32 (128KB)
  float*    BencT= (float*)(b5 + 299008);                 // 256x128 f32 (128KB)

  enc_mfma<0, 0, 1><<<dim3(68, 16), 256, 0, stream>>>(
      (const void*)ext, (const void*)w1a, b1a, g1a, be1a, (void*)Y1ab,
      (const void*)lab, (const void*)w2a, b2a, g2a, be2a, (void*)Y1bb,
      (float*)nullptr, 512, 352, 64);
  enc_mfma<1, 0, 0><<<dim3(68, 8), 256, 0, stream>>>(
      (const void*)Y1ab, (const void*)w1b, b1b, g1b, be1b, (void*)Aenc,
      (const void*)Y1bb, (const void*)w2b, b2b, g2b, be2b, (void*)Benc,
      BencT, 256, 512, 64);
  proj32<<<553, 256, 0, stream>>>(Aenc, Benc, mw1, mb1, mg1, mbe1, PA2, PB2, 512,
                                  mw2, mw3, mw2b, mw3b);
  main_attn<<<512, 256, 0, stream>>>(PA2, PB2, Aenc, BencT,
                                     mw2b, mb2, mg2, mbe2, mw3b, mb3, mg3, mbe3,
                                     fcw, fcb, (float*)d_out);
}